// Round 1
// baseline (38.740 us; speedup 1.0000x reference)
//
#include <hip/hip_runtime.h>

#define N_ 256
#define C_ 3
#define T_ 600
#define V_ 25
#define M_ 2
// per-(n,c) slab: T_*V_*M_ = 30000 floats, contiguous. As float2 (m-pair): T_*V_ = 15000.

__global__ void zero_ws_kernel(float* __restrict__ ws, int n) {
    int i = blockIdx.x * blockDim.x + threadIdx.x;
    if (i < n) ws[i] = 0.0f;
}

// One block per (n,c). blockDim = (32,16): tx<25 owns joint v=tx (float2 = both m),
// ty owns a contiguous t-chunk of 38. Rolling register carries x[t-1] for the
// temporal diff so x is loaded exactly once (plus 1 boundary load per chunk).
__global__ __launch_bounds__(512) void slab_kernel(const float* __restrict__ x,
                                                   const float* __restrict__ y,
                                                   float* __restrict__ absws,
                                                   float* __restrict__ sqws) {
    const int bid = blockIdx.x;       // n*3 + c
    const int n   = bid / C_;
    const int tx  = threadIdx.x;      // 0..31 (active < 25)
    const int ty  = threadIdx.y;      // 0..15

    const float2* __restrict__ xs = reinterpret_cast<const float2*>(x) + (size_t)bid * (T_ * V_);
    const float2* __restrict__ ys = reinterpret_cast<const float2*>(y) + (size_t)bid * (T_ * V_);

    float absacc = 0.0f, sqacc = 0.0f;

    if (tx < V_) {
        const int chunk = (T_ + 15) / 16;          // 38
        const int t0 = ty * chunk;
        const int t1 = (t0 + chunk < T_) ? (t0 + chunk) : T_;

        float2 xc = xs[t0 * V_ + tx];
        float2 yc = ys[t0 * V_ + tx];
        float ex = xc.x - yc.x, ey = xc.y - yc.y;
        sqacc = ex * ex + ey * ey;

        for (int t = t0 + 1; t < t1; ++t) {
            float2 xn = xs[t * V_ + tx];
            float2 yn = ys[t * V_ + tx];
            absacc += fabsf(xn.x - xc.x) + fabsf(xn.y - xc.y);
            ex = xn.x - yn.x; ey = xn.y - yn.y;
            sqacc += ex * ex + ey * ey;
            xc = xn;
        }
        if (t1 < T_) {                              // boundary motion pair (t1-1, t1)
            float2 xn = xs[t1 * V_ + tx];
            absacc += fabsf(xn.x - xc.x) + fabsf(xn.y - xc.y);
        }
    }

    __shared__ float redA[16][33];
    __shared__ float redS[16][33];
    redA[ty][tx] = absacc;
    redS[ty][tx] = sqacc;
    __syncthreads();

    if (ty == 0 && tx < V_) {
        float a = 0.0f, s = 0.0f;
        #pragma unroll
        for (int j = 0; j < 16; ++j) { a += redA[j][tx]; s += redS[j][tx]; }
        atomicAdd(&absws[n * V_ + tx], a);
        atomicAdd(&sqws[n * V_ + tx], s);
    }
}

// final = (1/TOT) * sum_n sum_v (V * abs[n,v] / sum_v abs[n,.]) * sq[n,v]
__global__ __launch_bounds__(256) void finalize_kernel(const float* __restrict__ absws,
                                                       const float* __restrict__ sqws,
                                                       float* __restrict__ out) {
    const int n = threadIdx.x;                      // 256 threads = 256 samples
    float sumAbs = 0.0f;
    #pragma unroll
    for (int v = 0; v < V_; ++v) sumAbs += absws[n * V_ + v];
    float sumW = 0.0f;
    #pragma unroll
    for (int v = 0; v < V_; ++v) sumW += absws[n * V_ + v] * sqws[n * V_ + v];
    float partial = (float)V_ * sumW / sumAbs;

    __shared__ float red[256];
    red[n] = partial;
    __syncthreads();
    for (int s = 128; s > 0; s >>= 1) {
        if (n < s) red[n] += red[n + s];
        __syncthreads();
    }
    if (n == 0) out[0] = red[0] / (float)((size_t)N_ * C_ * T_ * V_ * M_);
}

extern "C" void kernel_launch(void* const* d_in, const int* in_sizes, int n_in,
                              void* d_out, int out_size, void* d_ws, size_t ws_size,
                              hipStream_t stream) {
    const float* x = (const float*)d_in[0];
    const float* y = (const float*)d_in[1];
    float* out   = (float*)d_out;
    float* absws = (float*)d_ws;            // N*V floats
    float* sqws  = absws + N_ * V_;         // N*V floats

    const int nws = 2 * N_ * V_;            // 12800 floats
    zero_ws_kernel<<<(nws + 255) / 256, 256, 0, stream>>>(absws, nws);

    dim3 blk(32, 16);
    slab_kernel<<<N_ * C_, blk, 0, stream>>>(x, y, absws, sqws);

    finalize_kernel<<<1, 256, 0, stream>>>(absws, sqws, out);
}